// Round 4
// baseline (378.548 us; speedup 1.0000x reference)
//
#include <hip/hip_runtime.h>

#define Q_LBF 1e-4f
#define DTF   3600.0f
#define NN    131071
#define SENT  0x7FC00001u   // NaN sentinel: computed stream values are always finite
#define W1    2048          // S1 width = level-5 node count
#define W2    32            // S2 width = level-11 node count
#define PRESYNC_ROW 20      // consumer start-lag anchor (producer writes it at step 24)

#if __has_builtin(__builtin_amdgcn_exp2f)
#define FEXP2(x) __builtin_amdgcn_exp2f(x)
#else
#define FEXP2(x) exp2f(x)
#endif
#if __has_builtin(__builtin_amdgcn_logf)
#define FLOG2(x) __builtin_amdgcn_logf(x)
#else
#define FLOG2(x) log2f(x)
#endif
#if __has_builtin(__builtin_amdgcn_rcpf)
#define FRCP(x) __builtin_amdgcn_rcpf(x)
#else
#define FRCP(x) (1.0f/(x))
#endif

// Per-node time-invariant constants (everything except q folded once).
struct NC { float a1, e, tw, ssd, w2, a2, kd, kx; };

__device__ __forceinline__ NC make_nc(const float* __restrict__ nr,
                                      const float* __restrict__ qsr,
                                      const float* __restrict__ len,
                                      const float* __restrict__ slp,
                                      const float* __restrict__ twp,
                                      const float* __restrict__ ssp,
                                      const float* __restrict__ xsp,
                                      int g) {
  float n  = fmaf(nr[g], 0.34f, 0.01f);
  float qs = 3.0f * qsr[g];
  float s0 = fmaxf(slp[g], 1e-4f);
  float rs = sqrtf(s0);
  float L  = len[g];
  float x  = xsp[g];
  float ss = ssp[g];
  NC c;
  c.a1  = n * (qs + 1.0f) / fmaf(21.0f, rs, 1e-8f);
  c.e   = 3.0f / fmaf(3.0f, qs, 5.0f);
  c.tw  = twp[g];
  c.ssd = 2.0f * ss;
  c.w2  = 2.0f * sqrtf(fmaf(ss, ss, 1.0f));
  c.a2  = rs / n;
  float kl = 1.2f * L;
  c.kd  = kl * (1.0f - x);
  c.kx  = kl * x;
  return c;
}

__device__ __forceinline__ float node_b(const NC& c, float q, float qpc, float it,
                                        float& c1o) {
  float z    = q * c.a1;
  float d    = fmaxf(FEXP2(c.e * FLOG2(z)), 0.01f);
  float bot  = fmaxf(fmaf(-c.ssd, d, c.tw), 0.1f);
  float area = (c.tw + bot) * (0.5f * d);
  float wet  = fmaf(c.w2, d, bot);
  float R    = area * FRCP(wet);
  float v2   = c.a2 * FEXP2(0.66666668f * FLOG2(R));
  v2 = fminf(fmaxf(v2, 0.3f), 15.0f);
  float rv   = FRCP(v2);
  float rden = FRCP(fmaf(c.kd, rv, DTF));
  float c2   = fmaf(c.kx, rv, DTF) * rden;
  float c4   = 7200.0f * rden;
  c1o = c4 - c2;
  float c3 = 1.0f - c4;
  return fmaf(c2, it, fmaf(c3, q, c4 * qpc));
}

__device__ __forceinline__ int iclamp(int v, int lo, int hi) {
  return v < lo ? lo : (v > hi ? hi : v);
}

// Fence-free cross-XCD streaming via relaxed agent-scope atomics (bypass
// non-coherent L1/per-XCD-L2, operate at the LLC coherence point).
// One writer per word; 32-bit words can't tear; sentinel = "not written yet".
__device__ __forceinline__ void st_stream(float* p, float v) {
  __hip_atomic_store((unsigned*)p, __float_as_uint(v),
                     __ATOMIC_RELAXED, __HIP_MEMORY_SCOPE_AGENT);
}
__device__ __forceinline__ uint2 ld2_relaxed(const float* p) {
  const unsigned* u = (const unsigned*)p;
  uint2 r;
  r.x = __hip_atomic_load(u,     __ATOMIC_RELAXED, __HIP_MEMORY_SCOPE_AGENT);
  r.y = __hip_atomic_load(u + 1, __ATOMIC_RELAXED, __HIP_MEMORY_SCOPE_AGENT);
  return r;
}
__device__ __forceinline__ uint2 ld2_block(const float* p) {
  uint2 r = ld2_relaxed(p);
  while (r.x == SENT || r.y == SENT) {
    __builtin_amdgcn_s_sleep(1);
    r = ld2_relaxed(p);
  }
  return r;
}
// Plain (cacheable, fully pipelinable) 8B stream read. Safe after the one-time
// presync (write happens exactly once, strictly before first read); if the lag
// invariant ever breaks we read SENT and take the atomic blocking fallback.
__device__ __forceinline__ uint2 ld2_plain(const float* p) {
  return *reinterpret_cast<const uint2*>(p);
}

// ---- role A: levels 0..5, one depth-6 subtree per wave (2048 waves),
// ---- ONE node per lane: lanes 0-31 leaves, 32-47 L1, 48-55 L2, 56-59 L3,
// ---- 60-61 L4, 62(+63 dup) L5 root -> streams to S1 (width 2048).
__device__ __forceinline__ void run_A(
    const float* __restrict__ qp,
    const float* __restrict__ nr, const float* __restrict__ qsr,
    const float* __restrict__ len, const float* __restrict__ slp,
    const float* __restrict__ twp, const float* __restrict__ ssp,
    const float* __restrict__ xsp,
    float* __restrict__ S1, float* __restrict__ D1, int w, int lane) {
  int e, g, cs0;
  const bool leaf = lane < 32;
  if (leaf)           { e = 0; g = (w << 5) + lane;               cs0 = 0; }
  else if (lane < 48) { e = 1; g = 65536  + (w << 4) + (lane-32); cs0 = 2*(lane-32); }
  else if (lane < 56) { e = 2; g = 98304  + (w << 3) + (lane-48); cs0 = 32 + 2*(lane-48); }
  else if (lane < 60) { e = 3; g = 114688 + (w << 2) + (lane-56); cs0 = 48 + 2*(lane-56); }
  else if (lane < 62) { e = 4; g = 122880 + (w << 1) + (lane-60); cs0 = 56 + 2*(lane-60); }
  else                { e = 5; g = 126976 + w;                    cs0 = 60; }
  NC c = make_nc(nr,qsr,len,slp,twp,ssp,xsp, g);
  float q0 = qp[g];
  float i0 = __shfl(q0, cs0), i1 = __shfl(q0, cs0 + 1);
  const float itInit = i0 + i1;              // children's raw q_prime[0] (t=0 i_t)
  if (lane == 62) st_stream(&S1[w], q0);     // row 0 = raw q_prime[0] of L5 root
  float qc = q0, ul = q0, pu0 = 0.0f, pu1 = 0.0f;
  float rg[8];                               // distance-8 qp prefetch ring (VGPRs!)
#pragma unroll
  for (int j = 0; j < 8; ++j) rg[j] = qp[iclamp(j - e, 0, 335) * NN + g];
  int off = (8 - e) * NN + g;                // next fetch offset (8-e >= 3)
  const int offMax = 335 * NN + g;
  // 344 = 43 x 8; inner loop has literal trip count 8 -> fully unrolled,
  // every ring index compile-time constant (keeps rings in registers).
  for (int so = 0; so < 344; so += 8) {
#pragma unroll
    for (int j = 0; j < 8; ++j) {
      const int s = so + j;
      float u0 = __shfl(ul, cs0), u1 = __shfl(ul, cs0 + 1);
      float itg = (s == e) ? itInit : (fmaxf(pu0, Q_LBF) + fmaxf(pu1, Q_LBF));
      if (s == e) qc = q0;                   // epoch start: raw q_prime[0]
      float it  = leaf ? 0.0f : itg;
      float chn = leaf ? 0.0f : (u0 + u1);
      float qpc = fmaxf(rg[j], Q_LBF);
      float c1;
      float b  = node_b(c, qc, qpc, it, c1);
      float un = fmaf(c1, chn, b);
      qc = fmaxf(un, Q_LBF); ul = un;
      pu0 = u0; pu1 = u1;
      // unconditional store (static vm-op count): out-of-range -> dump word
      float* dst = (s >= 5 && s <= 339) ? (S1 + (s - 4) * W1 + w) : (D1 + w);
      if (lane == 62) st_stream(dst, un);
      rg[j] = qp[off];
      off = min(off + NN, offMax);
    }
  }
}

// ---- role B: levels 6..11, 32 waves; lanes 0-31 consume S1 pairs (level-6
// ---- nodes), lane 62 (L11 root) streams to S2 (width 32).
__device__ __forceinline__ void run_B(
    const float* __restrict__ qp,
    const float* __restrict__ nr, const float* __restrict__ qsr,
    const float* __restrict__ len, const float* __restrict__ slp,
    const float* __restrict__ twp, const float* __restrict__ ssp,
    const float* __restrict__ xsp,
    const float* __restrict__ S1, float* __restrict__ S2,
    float* __restrict__ D2, int r, int lane) {
  int e, g, cs0;
  const bool leaf = lane < 32;
  const int jl = leaf ? lane : 31;
  if (leaf)           { e = 0; g = 129024 + (r << 5) + lane;      cs0 = 0; }
  else if (lane < 48) { e = 1; g = 130048 + (r << 4) + (lane-32); cs0 = 2*(lane-32); }
  else if (lane < 56) { e = 2; g = 130560 + (r << 3) + (lane-48); cs0 = 32 + 2*(lane-48); }
  else if (lane < 60) { e = 3; g = 130816 + (r << 2) + (lane-56); cs0 = 48 + 2*(lane-56); }
  else if (lane < 62) { e = 4; g = 130944 + (r << 1) + (lane-60); cs0 = 56 + 2*(lane-60); }
  else                { e = 5; g = 131008 + r;                    cs0 = 60; }
  const int col2 = ((r << 5) + jl) * 2;      // child pair columns in S1 rows
  NC c = make_nc(nr,qsr,len,slp,twp,ssp,xsp, g);
  float q0 = qp[g];
  float i0 = __shfl(q0, cs0), i1 = __shfl(q0, cs0 + 1);
  const float itInit = i0 + i1;
  if (lane == 62) st_stream(&S2[r], q0);
  // ---- one-time start-lag sync: block until producer is >= 24 steps in.
  {
    uint2 t0 = ld2_block(S1 + PRESYNC_ROW * W1 + col2);
    asm volatile("" :: "v"(t0.x), "v"(t0.y));   // keep the sync load live
  }
  float qc = q0, ul = q0, pu0 = 0.0f, pu1 = 0.0f;
  uint2 rgs[8];                              // distance-8 PLAIN-load stream ring
  float rg[8];
#pragma unroll
  for (int j = 0; j < 8; ++j) rgs[j] = ld2_plain(S1 + iclamp(j, 0, 335) * W1 + col2);
#pragma unroll
  for (int j = 0; j < 8; ++j) rg[j] = qp[iclamp(j - e, 0, 335) * NN + g];
  int off = (8 - e) * NN + g;
  const int offMax = 335 * NN + g;
  int soff = 8 * W1 + col2;
  const int soffMax = 335 * W1 + col2;
  // Consumer priority: once fast, B must pace A during the A phase instead of
  // queueing behind it. Spin paths drop to prio 0 so co-resident A can't starve.
  __builtin_amdgcn_s_setprio(2);
  for (int so = 0; so < 344; so += 8) {
#pragma unroll
    for (int j = 0; j < 8; ++j) {
      const int s = so + j;
      uint2 fo = rgs[j];                     // row s   (old children state)
      uint2 fn = rgs[(j + 1) & 7];           // row s+1 (new children sweep)
      if (__builtin_expect((fo.x == SENT) | (fo.y == SENT) |
                           (fn.x == SENT) | (fn.y == SENT), 0)) {
        __builtin_amdgcn_s_setprio(0);
        fo = ld2_block(S1 + iclamp(s,     0, 335) * W1 + col2);
        fn = ld2_block(S1 + iclamp(s + 1, 0, 335) * W1 + col2);
        __builtin_amdgcn_s_setprio(2);
        rgs[(j + 1) & 7] = fn;               // fn becomes next iter's fo
      }
      float fox = __uint_as_float(fo.x), foy = __uint_as_float(fo.y);
      float fnx = __uint_as_float(fn.x), fny = __uint_as_float(fn.y);
      float u0 = __shfl(ul, cs0), u1 = __shfl(ul, cs0 + 1);
      float itg = (s == e) ? itInit : (fmaxf(pu0, Q_LBF) + fmaxf(pu1, Q_LBF));
      if (s == e) qc = q0;
      float it  = leaf ? (fmaxf(fox, Q_LBF) + fmaxf(foy, Q_LBF)) : itg;
      float chn = leaf ? (fnx + fny) : (u0 + u1);
      float qpc = fmaxf(rg[j], Q_LBF);
      float c1;
      float b  = node_b(c, qc, qpc, it, c1);
      float un = fmaf(c1, chn, b);
      qc = fmaxf(un, Q_LBF); ul = un;
      pu0 = u0; pu1 = u1;
      float* dst = (s >= 5 && s <= 339) ? (S2 + (s - 4) * W2 + r) : (D2 + r);
      if (lane == 62) st_stream(dst, un);
      rgs[j] = ld2_plain(S1 + soff);         // row s+8 -> slot (s+8)&7 == j
      rg[j]  = qp[off];
      off  = min(off + NN, offMax);
      soff = min(soff + W1, soffMax);
    }
  }
  __builtin_amdgcn_s_setprio(0);
}

// ---- role C: levels 12..16, one wave; lanes 0-15 consume S2 pairs (level-12
// ---- nodes), lane 30 (root) writes out[0..335].
__device__ __forceinline__ void run_C(
    const float* __restrict__ qp,
    const float* __restrict__ nr, const float* __restrict__ qsr,
    const float* __restrict__ len, const float* __restrict__ slp,
    const float* __restrict__ twp, const float* __restrict__ ssp,
    const float* __restrict__ xsp,
    const float* __restrict__ S2, float* __restrict__ out, int lane) {
  int e, g, cs0;
  const bool leaf = lane < 16;
  const int jl = leaf ? lane : 15;
  if (leaf)           { e = 0; g = 131040 + lane;        cs0 = 0; }
  else if (lane < 24) { e = 1; g = 131056 + (lane - 16); cs0 = 2*(lane-16); }
  else if (lane < 28) { e = 2; g = 131064 + (lane - 24); cs0 = 16 + 2*(lane-24); }
  else if (lane < 30) { e = 3; g = 131068 + (lane - 28); cs0 = 24 + 2*(lane-28); }
  else                { e = 4; g = 131070;               cs0 = 28; }
  const int col2 = jl * 2;                   // child pair columns in S2 rows
  NC c = make_nc(nr,qsr,len,slp,twp,ssp,xsp, g);
  float q0 = qp[g];
  float i0 = __shfl(q0, cs0), i1 = __shfl(q0, cs0 + 1);
  const float itInit = i0 + i1;
  if (lane == 30) out[0] = fmaxf(q0, Q_LBF);
  // ---- one-time start-lag sync against role B (see run_B comment).
  {
    uint2 t0 = ld2_block(S2 + PRESYNC_ROW * W2 + col2);
    asm volatile("" :: "v"(t0.x), "v"(t0.y));
  }
  float qc = q0, ul = q0, pu0 = 0.0f, pu1 = 0.0f;
  uint2 rgs[8];
  float rg[8];
#pragma unroll
  for (int j = 0; j < 8; ++j) rgs[j] = ld2_plain(S2 + iclamp(j, 0, 335) * W2 + col2);
#pragma unroll
  for (int j = 0; j < 8; ++j) rg[j] = qp[iclamp(j - e, 0, 335) * NN + g];
  int off = (8 - e) * NN + g;
  const int offMax = 335 * NN + g;
  int soff = 8 * W2 + col2;
  const int soffMax = 335 * W2 + col2;
  __builtin_amdgcn_s_setprio(3);
  for (int so = 0; so < 344; so += 8) {
#pragma unroll
    for (int j = 0; j < 8; ++j) {
      const int s = so + j;
      uint2 fo = rgs[j];
      uint2 fn = rgs[(j + 1) & 7];
      if (__builtin_expect((fo.x == SENT) | (fo.y == SENT) |
                           (fn.x == SENT) | (fn.y == SENT), 0)) {
        __builtin_amdgcn_s_setprio(0);
        fo = ld2_block(S2 + iclamp(s,     0, 335) * W2 + col2);
        fn = ld2_block(S2 + iclamp(s + 1, 0, 335) * W2 + col2);
        __builtin_amdgcn_s_setprio(3);
        rgs[(j + 1) & 7] = fn;
      }
      float fox = __uint_as_float(fo.x), foy = __uint_as_float(fo.y);
      float fnx = __uint_as_float(fn.x), fny = __uint_as_float(fn.y);
      float u0 = __shfl(ul, cs0), u1 = __shfl(ul, cs0 + 1);
      float itg = (s == e) ? itInit : (fmaxf(pu0, Q_LBF) + fmaxf(pu1, Q_LBF));
      if (s == e) qc = q0;
      float it  = leaf ? (fmaxf(fox, Q_LBF) + fmaxf(foy, Q_LBF)) : itg;
      float chn = leaf ? (fnx + fny) : (u0 + u1);
      float qpc = fmaxf(rg[j], Q_LBF);
      float c1;
      float b  = node_b(c, qc, qpc, it, c1);
      float un = fmaf(c1, chn, b);
      qc = fmaxf(un, Q_LBF); ul = un;
      pu0 = u0; pu1 = u1;
      if (lane == 30 && s >= 4 && s <= 338) out[s - 3] = fmaxf(un, Q_LBF);
      rgs[j] = ld2_plain(S2 + soff);
      rg[j]  = qp[off];
      off  = min(off + NN, offMax);
      soff = min(soff + W2, soffMax);
    }
  }
  __builtin_amdgcn_s_setprio(0);
}

__global__ __launch_bounds__(256) void kinit(unsigned* __restrict__ F, int n) {
  int i = blockIdx.x * 256 + threadIdx.x;
  int stride = gridDim.x * 256;
  for (; i < n; i += stride) F[i] = SENT;
}

__global__ __launch_bounds__(512) void fused(
    const float* __restrict__ qp,
    const float* __restrict__ nr, const float* __restrict__ qsr,
    const float* __restrict__ len, const float* __restrict__ slp,
    const float* __restrict__ twp, const float* __restrict__ ssp,
    const float* __restrict__ xsp,
    float* __restrict__ S1, float* __restrict__ S2,
    float* __restrict__ D1, float* __restrict__ D2,
    float* __restrict__ out) {
  const int wv = threadIdx.x >> 6;
  const int lane = threadIdx.x & 63;
  const int b = blockIdx.x;
  if (b < 256) {
    run_A(qp, nr, qsr, len, slp, twp, ssp, xsp, S1, D1, (b << 3) + wv, lane);
  } else if (b < 260) {
    run_B(qp, nr, qsr, len, slp, twp, ssp, xsp, S1, S2, D2,
          ((b - 256) << 3) + wv, lane);
  } else if (wv == 0) {
    run_C(qp, nr, qsr, len, slp, twp, ssp, xsp, S2, out, lane);
  }
}

extern "C" void kernel_launch(void* const* d_in, const int* in_sizes, int n_in,
                              void* d_out, int out_size, void* d_ws, size_t ws_size,
                              hipStream_t stream) {
  const float* q_prime = (const float*)d_in[0];
  const float* n_raw   = (const float*)d_in[1];
  const float* qs_raw  = (const float*)d_in[2];
  const float* length  = (const float*)d_in[3];
  const float* slope   = (const float*)d_in[4];
  const float* tw      = (const float*)d_in[5];
  const float* ss      = (const float*)d_in[6];
  const float* xs      = (const float*)d_in[7];
  float* out = (float*)d_out;
  float* S1 = (float*)d_ws;                  // 336 x 2048 level-5 series
  float* S2 = S1 + 336 * W1;                 // 336 x 32 level-11 series
  float* D1 = S2 + 336 * W2;                 // 2048-word dump (out-of-range A stores)
  float* D2 = D1 + W1;                       // 32-word dump (out-of-range B stores)
  const int nsent = 336 * W1 + 336 * W2 + W1 + W2;   // ~2.8 MB of workspace
  kinit<<<128, 256, 0, stream>>>((unsigned*)d_ws, nsent);
  fused<<<261, 512, 0, stream>>>(q_prime, n_raw, qs_raw, length, slope, tw, ss, xs,
                                 S1, S2, D1, D2, out);
}

// Round 5
// 329.603 us; speedup vs baseline: 1.1485x; 1.1485x over previous
//
#include <hip/hip_runtime.h>

#define Q_LBF 1e-4f
#define DTF   3600.0f
#define NN    131071
#define SENT  0x7FC00001u   // NaN sentinel: computed stream values are always finite
#define W1    2048          // S1 width = level-5 node count
#define W2    32            // S2 width = level-11 node count
#define PRESYNC_ROW 20      // consumer start-lag anchor (producer writes it at step 24)

#if __has_builtin(__builtin_amdgcn_exp2f)
#define FEXP2(x) __builtin_amdgcn_exp2f(x)
#else
#define FEXP2(x) exp2f(x)
#endif
#if __has_builtin(__builtin_amdgcn_logf)
#define FLOG2(x) __builtin_amdgcn_logf(x)
#else
#define FLOG2(x) log2f(x)
#endif
#if __has_builtin(__builtin_amdgcn_rcpf)
#define FRCP(x) __builtin_amdgcn_rcpf(x)
#else
#define FRCP(x) (1.0f/(x))
#endif

// Per-node time-invariant constants (everything except q folded once).
struct NC { float a1, e, tw, ssd, w2, a2, kd, kx; };

__device__ __forceinline__ NC make_nc(const float* __restrict__ nr,
                                      const float* __restrict__ qsr,
                                      const float* __restrict__ len,
                                      const float* __restrict__ slp,
                                      const float* __restrict__ twp,
                                      const float* __restrict__ ssp,
                                      const float* __restrict__ xsp,
                                      int g) {
  float n  = fmaf(nr[g], 0.34f, 0.01f);
  float qs = 3.0f * qsr[g];
  float s0 = fmaxf(slp[g], 1e-4f);
  float rs = sqrtf(s0);
  float L  = len[g];
  float x  = xsp[g];
  float ss = ssp[g];
  NC c;
  c.a1  = n * (qs + 1.0f) / fmaf(21.0f, rs, 1e-8f);
  c.e   = 3.0f / fmaf(3.0f, qs, 5.0f);
  c.tw  = twp[g];
  c.ssd = 2.0f * ss;
  c.w2  = 2.0f * sqrtf(fmaf(ss, ss, 1.0f));
  c.a2  = rs / n;
  float kl = 1.2f * L;
  c.kd  = kl * (1.0f - x);
  c.kx  = kl * x;
  return c;
}

__device__ __forceinline__ float node_b(const NC& c, float q, float qpc, float it,
                                        float& c1o) {
  float z    = q * c.a1;
  float d    = fmaxf(FEXP2(c.e * FLOG2(z)), 0.01f);
  float bot  = fmaxf(fmaf(-c.ssd, d, c.tw), 0.1f);
  float area = (c.tw + bot) * (0.5f * d);
  float wet  = fmaf(c.w2, d, bot);
  float R    = area * FRCP(wet);
  float v2   = c.a2 * FEXP2(0.66666668f * FLOG2(R));
  v2 = fminf(fmaxf(v2, 0.3f), 15.0f);
  float rv   = FRCP(v2);
  float rden = FRCP(fmaf(c.kd, rv, DTF));
  float c2   = fmaf(c.kx, rv, DTF) * rden;
  float c4   = 7200.0f * rden;
  c1o = c4 - c2;
  float c3 = 1.0f - c4;
  return fmaf(c2, it, fmaf(c3, q, c4 * qpc));
}

__device__ __forceinline__ int iclamp(int v, int lo, int hi) {
  return v < lo ? lo : (v > hi ? hi : v);
}

// Fence-free cross-XCD streaming via relaxed agent-scope atomics (bypass
// non-coherent L1/per-XCD-L2, operate at the LLC coherence point).
// One writer per word; 32-bit words can't tear; sentinel = "not written yet".
__device__ __forceinline__ void st_stream(float* p, float v) {
  __hip_atomic_store((unsigned*)p, __float_as_uint(v),
                     __ATOMIC_RELAXED, __HIP_MEMORY_SCOPE_AGENT);
}
__device__ __forceinline__ uint2 ld2_relaxed(const float* p) {
  const unsigned* u = (const unsigned*)p;
  uint2 r;
  r.x = __hip_atomic_load(u,     __ATOMIC_RELAXED, __HIP_MEMORY_SCOPE_AGENT);
  r.y = __hip_atomic_load(u + 1, __ATOMIC_RELAXED, __HIP_MEMORY_SCOPE_AGENT);
  return r;
}
__device__ __forceinline__ uint2 ld2_block(const float* p) {
  uint2 r = ld2_relaxed(p);
  while (r.x == SENT || r.y == SENT) {
    __builtin_amdgcn_s_sleep(1);
    r = ld2_relaxed(p);
  }
  return r;
}
// Plain (cacheable, fully pipelinable) 8B stream read. Safe after the one-time
// presync (write happens exactly once, strictly before first read); if the lag
// invariant ever breaks we read SENT and take the atomic blocking fallback.
__device__ __forceinline__ uint2 ld2_plain(const float* p) {
  return *reinterpret_cast<const uint2*>(p);
}

// ---- role A: levels 0..5, one depth-6 subtree per wave (2048 waves),
// ---- ONE node per lane: lanes 0-31 leaves, 32-47 L1, 48-55 L2, 56-59 L3,
// ---- 60-61 L4, 62(+63 dup) L5 root -> streams to S1 (width 2048).
__device__ __forceinline__ void run_A(
    const float* __restrict__ qp,
    const float* __restrict__ nr, const float* __restrict__ qsr,
    const float* __restrict__ len, const float* __restrict__ slp,
    const float* __restrict__ twp, const float* __restrict__ ssp,
    const float* __restrict__ xsp,
    float* __restrict__ S1, float* __restrict__ D1, int w, int lane) {
  int e, g, cs0;
  const bool leaf = lane < 32;
  if (leaf)           { e = 0; g = (w << 5) + lane;               cs0 = 0; }
  else if (lane < 48) { e = 1; g = 65536  + (w << 4) + (lane-32); cs0 = 2*(lane-32); }
  else if (lane < 56) { e = 2; g = 98304  + (w << 3) + (lane-48); cs0 = 32 + 2*(lane-48); }
  else if (lane < 60) { e = 3; g = 114688 + (w << 2) + (lane-56); cs0 = 48 + 2*(lane-56); }
  else if (lane < 62) { e = 4; g = 122880 + (w << 1) + (lane-60); cs0 = 56 + 2*(lane-60); }
  else                { e = 5; g = 126976 + w;                    cs0 = 60; }
  NC c = make_nc(nr,qsr,len,slp,twp,ssp,xsp, g);
  float q0 = qp[g];
  float i0 = __shfl(q0, cs0), i1 = __shfl(q0, cs0 + 1);
  const float itInit = i0 + i1;              // children's raw q_prime[0] (t=0 i_t)
  if (lane == 62) st_stream(&S1[w], q0);     // row 0 = raw q_prime[0] of L5 root
  float qc = q0, ul = q0, pu0 = 0.0f, pu1 = 0.0f;
  float rg[8];                               // distance-8 qp prefetch ring (VGPRs)
#pragma unroll
  for (int j = 0; j < 8; ++j) rg[j] = qp[iclamp(j - e, 0, 335) * NN + g];
  int off = (8 - e) * NN + g;                // next fetch offset (8-e >= 3)
  const int offMax = 335 * NN + g;
  // 344 = 43 x 8; inner loop fully unrolled, ring indices compile-time const.
  for (int so = 0; so < 344; so += 8) {
#pragma unroll
    for (int j = 0; j < 8; ++j) {
      const int s = so + j;
      float u0 = __shfl(ul, cs0), u1 = __shfl(ul, cs0 + 1);
      float itg = (s == e) ? itInit : (fmaxf(pu0, Q_LBF) + fmaxf(pu1, Q_LBF));
      if (s == e) qc = q0;                   // epoch start: raw q_prime[0]
      float it  = leaf ? 0.0f : itg;
      float chn = leaf ? 0.0f : (u0 + u1);
      float qpc = fmaxf(rg[j], Q_LBF);
      float c1;
      float b  = node_b(c, qc, qpc, it, c1);
      float un = fmaf(c1, chn, b);
      qc = fmaxf(un, Q_LBF); ul = un;
      pu0 = u0; pu1 = u1;
      // unconditional store (static vm-op count): out-of-range -> dump word
      float* dst = (s >= 5 && s <= 339) ? (S1 + (s - 4) * W1 + w) : (D1 + w);
      if (lane == 62) st_stream(dst, un);
      rg[j] = qp[off];
      off = min(off + NN, offMax);
    }
  }
}

// ---- role B: levels 6..11, 32 waves; lanes 0-31 consume S1 pairs (level-6
// ---- nodes), lane 62 (L11 root) streams to S2 (width 32).
__device__ __forceinline__ void run_B(
    const float* __restrict__ qp,
    const float* __restrict__ nr, const float* __restrict__ qsr,
    const float* __restrict__ len, const float* __restrict__ slp,
    const float* __restrict__ twp, const float* __restrict__ ssp,
    const float* __restrict__ xsp,
    const float* __restrict__ S1, float* __restrict__ S2,
    float* __restrict__ D2, int r, int lane) {
  int e, g, cs0;
  const bool leaf = lane < 32;
  const int jl = leaf ? lane : 31;
  if (leaf)           { e = 0; g = 129024 + (r << 5) + lane;      cs0 = 0; }
  else if (lane < 48) { e = 1; g = 130048 + (r << 4) + (lane-32); cs0 = 2*(lane-32); }
  else if (lane < 56) { e = 2; g = 130560 + (r << 3) + (lane-48); cs0 = 32 + 2*(lane-48); }
  else if (lane < 60) { e = 3; g = 130816 + (r << 2) + (lane-56); cs0 = 48 + 2*(lane-56); }
  else if (lane < 62) { e = 4; g = 130944 + (r << 1) + (lane-60); cs0 = 56 + 2*(lane-60); }
  else                { e = 5; g = 131008 + r;                    cs0 = 60; }
  const int col2 = ((r << 5) + jl) * 2;      // child pair columns in S1 rows
  NC c = make_nc(nr,qsr,len,slp,twp,ssp,xsp, g);
  float q0 = qp[g];
  float i0 = __shfl(q0, cs0), i1 = __shfl(q0, cs0 + 1);
  const float itInit = i0 + i1;
  if (lane == 62) st_stream(&S2[r], q0);
  // ---- one-time start-lag sync: block until producer is >= 24 steps in.
  {
    uint2 t0 = ld2_block(S1 + PRESYNC_ROW * W1 + col2);
    asm volatile("" :: "v"(t0.x), "v"(t0.y));   // keep the sync load live
  }
  float qc = q0, ul = q0, pu0 = 0.0f, pu1 = 0.0f;
  uint2 rgs[8];                              // distance-8 PLAIN-load stream ring
  float rg[8];
#pragma unroll
  for (int j = 0; j < 8; ++j) rgs[j] = ld2_plain(S1 + iclamp(j, 0, 335) * W1 + col2);
#pragma unroll
  for (int j = 0; j < 8; ++j) rg[j] = qp[iclamp(j - e, 0, 335) * NN + g];
  int off = (8 - e) * NN + g;
  const int offMax = 335 * NN + g;
  int soff = 8 * W1 + col2;
  const int soffMax = 335 * W1 + col2;
  // Consumer priority: B must pace A instead of queueing behind its 8
  // co-resident A waves. Spin paths drop to prio 0.
  __builtin_amdgcn_s_setprio(2);
  for (int so = 0; so < 344; so += 8) {
#pragma unroll
    for (int j = 0; j < 8; ++j) {
      const int s = so + j;
      uint2 fo = rgs[j];                     // row s   (old children state)
      uint2 fn = rgs[(j + 1) & 7];           // row s+1 (new children sweep)
      if (__builtin_expect((fo.x == SENT) | (fo.y == SENT) |
                           (fn.x == SENT) | (fn.y == SENT), 0)) {
        __builtin_amdgcn_s_setprio(0);
        fo = ld2_block(S1 + iclamp(s,     0, 335) * W1 + col2);
        fn = ld2_block(S1 + iclamp(s + 1, 0, 335) * W1 + col2);
        __builtin_amdgcn_s_setprio(2);
        rgs[(j + 1) & 7] = fn;               // fn becomes next iter's fo
      }
      float fox = __uint_as_float(fo.x), foy = __uint_as_float(fo.y);
      float fnx = __uint_as_float(fn.x), fny = __uint_as_float(fn.y);
      float u0 = __shfl(ul, cs0), u1 = __shfl(ul, cs0 + 1);
      float itg = (s == e) ? itInit : (fmaxf(pu0, Q_LBF) + fmaxf(pu1, Q_LBF));
      if (s == e) qc = q0;
      float it  = leaf ? (fmaxf(fox, Q_LBF) + fmaxf(foy, Q_LBF)) : itg;
      float chn = leaf ? (fnx + fny) : (u0 + u1);
      float qpc = fmaxf(rg[j], Q_LBF);
      float c1;
      float b  = node_b(c, qc, qpc, it, c1);
      float un = fmaf(c1, chn, b);
      qc = fmaxf(un, Q_LBF); ul = un;
      pu0 = u0; pu1 = u1;
      float* dst = (s >= 5 && s <= 339) ? (S2 + (s - 4) * W2 + r) : (D2 + r);
      if (lane == 62) st_stream(dst, un);
      rgs[j] = ld2_plain(S1 + soff);         // row s+8 -> slot (s+8)&7 == j
      rg[j]  = qp[off];
      off  = min(off + NN, offMax);
      soff = min(soff + W1, soffMax);
    }
  }
  __builtin_amdgcn_s_setprio(0);
}

// ---- role C: levels 12..16, one wave; lanes 0-15 consume S2 pairs (level-12
// ---- nodes), lane 30 (root) writes out[0..335].
__device__ __forceinline__ void run_C(
    const float* __restrict__ qp,
    const float* __restrict__ nr, const float* __restrict__ qsr,
    const float* __restrict__ len, const float* __restrict__ slp,
    const float* __restrict__ twp, const float* __restrict__ ssp,
    const float* __restrict__ xsp,
    const float* __restrict__ S2, float* __restrict__ out, int lane) {
  int e, g, cs0;
  const bool leaf = lane < 16;
  const int jl = leaf ? lane : 15;
  if (leaf)           { e = 0; g = 131040 + lane;        cs0 = 0; }
  else if (lane < 24) { e = 1; g = 131056 + (lane - 16); cs0 = 2*(lane-16); }
  else if (lane < 28) { e = 2; g = 131064 + (lane - 24); cs0 = 16 + 2*(lane-24); }
  else if (lane < 30) { e = 3; g = 131068 + (lane - 28); cs0 = 24 + 2*(lane-28); }
  else                { e = 4; g = 131070;               cs0 = 28; }
  const int col2 = jl * 2;                   // child pair columns in S2 rows
  NC c = make_nc(nr,qsr,len,slp,twp,ssp,xsp, g);
  float q0 = qp[g];
  float i0 = __shfl(q0, cs0), i1 = __shfl(q0, cs0 + 1);
  const float itInit = i0 + i1;
  if (lane == 30) out[0] = fmaxf(q0, Q_LBF);
  // ---- one-time start-lag sync against role B (see run_B comment).
  {
    uint2 t0 = ld2_block(S2 + PRESYNC_ROW * W2 + col2);
    asm volatile("" :: "v"(t0.x), "v"(t0.y));
  }
  float qc = q0, ul = q0, pu0 = 0.0f, pu1 = 0.0f;
  uint2 rgs[8];
  float rg[8];
#pragma unroll
  for (int j = 0; j < 8; ++j) rgs[j] = ld2_plain(S2 + iclamp(j, 0, 335) * W2 + col2);
#pragma unroll
  for (int j = 0; j < 8; ++j) rg[j] = qp[iclamp(j - e, 0, 335) * NN + g];
  int off = (8 - e) * NN + g;
  const int offMax = 335 * NN + g;
  int soff = 8 * W2 + col2;
  const int soffMax = 335 * W2 + col2;
  __builtin_amdgcn_s_setprio(3);
  for (int so = 0; so < 344; so += 8) {
#pragma unroll
    for (int j = 0; j < 8; ++j) {
      const int s = so + j;
      uint2 fo = rgs[j];
      uint2 fn = rgs[(j + 1) & 7];
      if (__builtin_expect((fo.x == SENT) | (fo.y == SENT) |
                           (fn.x == SENT) | (fn.y == SENT), 0)) {
        __builtin_amdgcn_s_setprio(0);
        fo = ld2_block(S2 + iclamp(s,     0, 335) * W2 + col2);
        fn = ld2_block(S2 + iclamp(s + 1, 0, 335) * W2 + col2);
        __builtin_amdgcn_s_setprio(3);
        rgs[(j + 1) & 7] = fn;
      }
      float fox = __uint_as_float(fo.x), foy = __uint_as_float(fo.y);
      float fnx = __uint_as_float(fn.x), fny = __uint_as_float(fn.y);
      float u0 = __shfl(ul, cs0), u1 = __shfl(ul, cs0 + 1);
      float itg = (s == e) ? itInit : (fmaxf(pu0, Q_LBF) + fmaxf(pu1, Q_LBF));
      if (s == e) qc = q0;
      float it  = leaf ? (fmaxf(fox, Q_LBF) + fmaxf(foy, Q_LBF)) : itg;
      float chn = leaf ? (fnx + fny) : (u0 + u1);
      float qpc = fmaxf(rg[j], Q_LBF);
      float c1;
      float b  = node_b(c, qc, qpc, it, c1);
      float un = fmaf(c1, chn, b);
      qc = fmaxf(un, Q_LBF); ul = un;
      pu0 = u0; pu1 = u1;
      if (lane == 30 && s >= 4 && s <= 338) out[s - 3] = fmaxf(un, Q_LBF);
      rgs[j] = ld2_plain(S2 + soff);
      rg[j]  = qp[off];
      off  = min(off + NN, offMax);
      soff = min(soff + W2, soffMax);
    }
  }
  __builtin_amdgcn_s_setprio(0);
}

__global__ __launch_bounds__(256) void kinit(unsigned* __restrict__ F, int n) {
  int i = blockIdx.x * 256 + threadIdx.x;
  int stride = gridDim.x * 256;
  for (; i < n; i += stride) F[i] = SENT;
}

// 256 blocks x 9 waves (576 thr): waves 0-7 = A (2048 waves), wave 8 = B on
// blocks 0-31, C on block 32. One block per CU -> all roles co-resident from
// t=0. launch_bounds(576,3): 3 waves/SIMD min -> VGPR cap ~168, enough for the
// 8-deep prefetch rings to live in registers (the whole point of this round).
__global__ __launch_bounds__(576, 3) void fused(
    const float* __restrict__ qp,
    const float* __restrict__ nr, const float* __restrict__ qsr,
    const float* __restrict__ len, const float* __restrict__ slp,
    const float* __restrict__ twp, const float* __restrict__ ssp,
    const float* __restrict__ xsp,
    float* __restrict__ S1, float* __restrict__ S2,
    float* __restrict__ D1, float* __restrict__ D2,
    float* __restrict__ out) {
  const int wv = threadIdx.x >> 6;
  const int lane = threadIdx.x & 63;
  const int b = blockIdx.x;
  if (wv < 8) {
    run_A(qp, nr, qsr, len, slp, twp, ssp, xsp, S1, D1, (b << 3) + wv, lane);
  } else if (b < 32) {
    run_B(qp, nr, qsr, len, slp, twp, ssp, xsp, S1, S2, D2, b, lane);
  } else if (b == 32) {
    run_C(qp, nr, qsr, len, slp, twp, ssp, xsp, S2, out, lane);
  }
}

extern "C" void kernel_launch(void* const* d_in, const int* in_sizes, int n_in,
                              void* d_out, int out_size, void* d_ws, size_t ws_size,
                              hipStream_t stream) {
  const float* q_prime = (const float*)d_in[0];
  const float* n_raw   = (const float*)d_in[1];
  const float* qs_raw  = (const float*)d_in[2];
  const float* length  = (const float*)d_in[3];
  const float* slope   = (const float*)d_in[4];
  const float* tw      = (const float*)d_in[5];
  const float* ss      = (const float*)d_in[6];
  const float* xs      = (const float*)d_in[7];
  float* out = (float*)d_out;
  float* S1 = (float*)d_ws;                  // 336 x 2048 level-5 series
  float* S2 = S1 + 336 * W1;                 // 336 x 32 level-11 series
  float* D1 = S2 + 336 * W2;                 // 2048-word dump (out-of-range A stores)
  float* D2 = D1 + W1;                       // 32-word dump (out-of-range B stores)
  const int nsent = 336 * W1 + 336 * W2 + W1 + W2;   // ~2.8 MB of workspace
  kinit<<<128, 256, 0, stream>>>((unsigned*)d_ws, nsent);
  fused<<<256, 576, 0, stream>>>(q_prime, n_raw, qs_raw, length, slope, tw, ss, xs,
                                 S1, S2, D1, D2, out);
}